// Round 3
// baseline (367.765 us; speedup 1.0000x reference)
//
#include <hip/hip_runtime.h>

// LengthRegulator: B=64, S=1024, D=512, T=2048 (fixed by setup_inputs)
constexpr int B = 64;
constexpr int S = 1024;
constexpr int D = 512;
constexpr int T = 2048;
constexpr int FPB = 64;            // frames per block (copy kernel)
constexpr int CHUNKS = T / FPB;    // 32

typedef float floatx4 __attribute__((ext_vector_type(4)));   // true vector type for nontemporal builtins

// ---------------- Kernel A: cumsum + searchsorted + mask (64 blocks) --------
__global__ __launch_bounds__(256) void lr_scan_kernel(
    const int* __restrict__ dur,    // [B, S]
    int*       __restrict__ fidx,   // [B, T]  (ws)  -1 => masked/zero row
    float*     __restrict__ mask)   // [B, T]
{
    __shared__ int cum[S];
    __shared__ int part[256];

    const int tid = threadIdx.x;
    const int b   = blockIdx.x;

    const int4 d4 = ((const int4*)(dur + b * S))[tid];
    const int p0 = d4.x;
    const int p1 = p0 + d4.y;
    const int p2 = p1 + d4.z;
    const int p3 = p2 + d4.w;

    part[tid] = p3;
    __syncthreads();
    int incl = p3;
    for (int off = 1; off < 256; off <<= 1) {
        const int v = (tid >= off) ? part[tid - off] : 0;
        __syncthreads();
        incl += v;
        part[tid] = incl;
        __syncthreads();
    }
    const int excl = incl - p3;
    cum[4 * tid + 0] = excl + p0;
    cum[4 * tid + 1] = excl + p1;
    cum[4 * tid + 2] = excl + p2;
    cum[4 * tid + 3] = excl + p3;
    __syncthreads();
    const int len = cum[S - 1];

    #pragma unroll
    for (int k = 0; k < T / 256; ++k) {
        const int t = k * 256 + tid;
        int id = -1;
        if (t < len) {
            int lo = 0, hi = S;
            while (lo < hi) {
                const int mid = (lo + hi) >> 1;
                if (cum[mid] > t) hi = mid; else lo = mid + 1;
            }
            id = lo;                 // <= S-1 since cum[S-1] = len > t
        }
        fidx[b * T + t] = id;
        __builtin_nontemporal_store((id < 0) ? 1.0f : 0.0f, &mask[b * T + t]);
    }
}

// ---------------- Kernel B: pure streaming gather-copy ----------------------
__global__ __launch_bounds__(256) void lr_copy_kernel(
    const float* __restrict__ x,     // [B, S, D]
    const int*   __restrict__ fidx,  // [B, T]
    float*       __restrict__ out)   // [B, T, D]
{
    __shared__ int fr[FPB];

    const int tid   = threadIdx.x;
    const int chunk = blockIdx.x;
    const int b     = blockIdx.y;
    const int t0    = chunk * FPB;

    if (tid < FPB) fr[tid] = fidx[b * T + t0 + tid];
    __syncthreads();

    const int sub = tid >> 7;        // which of 2 frames per iteration
    const int j   = tid & 127;       // float4 index within row (D/4 = 128)
    const floatx4* xb = (const floatx4*)(x + (size_t)b * S * D);
    floatx4*       ob = (floatx4*)(out + ((size_t)b * T + t0) * D);

    #pragma unroll 8
    for (int it = 0; it < FPB / 2; ++it) {
        const int tl = it * 2 + sub;
        const int id = fr[tl];
        floatx4 v = (floatx4)(0.f);
        if (id >= 0) v = xb[(size_t)id * (D / 4) + j];
        __builtin_nontemporal_store(v, &ob[(size_t)tl * (D / 4) + j]);
    }
}

extern "C" void kernel_launch(void* const* d_in, const int* in_sizes, int n_in,
                              void* d_out, int out_size, void* d_ws, size_t ws_size,
                              hipStream_t stream) {
    const float* x   = (const float*)d_in[0];
    const int*   dur = (const int*)d_in[1];
    float* out  = (float*)d_out;
    float* mask = out + (size_t)B * T * D;   // outputs concatenated flat
    int*   fidx = (int*)d_ws;                // 512 KB scratch

    lr_scan_kernel<<<B, 256, 0, stream>>>(dur, fidx, mask);
    dim3 grid(CHUNKS, B);
    lr_copy_kernel<<<grid, 256, 0, stream>>>(x, fidx, out);
}

// Round 4
// 359.873 us; speedup vs baseline: 1.0219x; 1.0219x over previous
//
#include <hip/hip_runtime.h>

// LengthRegulator: B=64, S=1024, D=512, T=2048 (fixed by setup_inputs)
constexpr int B = 64;
constexpr int S = 1024;
constexpr int D = 512;
constexpr int T = 2048;
constexpr int FPB = 64;            // frames per block (copy kernel)
constexpr int CHUNKS = T / FPB;    // 32

typedef float floatx4 __attribute__((ext_vector_type(4)));

// ---------------- Kernel A: cumsum + searchsorted + mask (64 blocks) --------
__global__ __launch_bounds__(256) void lr_scan_kernel(
    const int* __restrict__ dur,    // [B, S]
    int*       __restrict__ fidx,   // [B, T]  (ws)  -1 => masked/zero row
    float*     __restrict__ mask)   // [B, T]
{
    __shared__ int cum[S];
    __shared__ int wave_tot[4];

    const int tid  = threadIdx.x;
    const int b    = blockIdx.x;
    const int lane = tid & 63;
    const int wv   = tid >> 6;

    const int4 d4 = ((const int4*)(dur + b * S))[tid];
    const int p0 = d4.x;
    const int p1 = p0 + d4.y;
    const int p2 = p1 + d4.z;
    const int p3 = p2 + d4.w;

    // shuffle-based inclusive scan of per-thread totals within each wave
    int incl = p3;
    #pragma unroll
    for (int off = 1; off < 64; off <<= 1) {
        const int v = __shfl_up(incl, off, 64);
        if (lane >= off) incl += v;
    }
    if (lane == 63) wave_tot[wv] = incl;   // wave total
    __syncthreads();
    int woff = 0;
    #pragma unroll
    for (int w = 0; w < 4; ++w) woff += (w < wv) ? wave_tot[w] : 0;

    const int excl = woff + incl - p3;     // exclusive prefix for this thread's 4 elems
    cum[4 * tid + 0] = excl + p0;
    cum[4 * tid + 1] = excl + p1;
    cum[4 * tid + 2] = excl + p2;
    cum[4 * tid + 3] = excl + p3;
    __syncthreads();
    const int len = cum[S - 1];

    #pragma unroll
    for (int k = 0; k < T / 256; ++k) {
        const int t = k * 256 + tid;
        int id = -1;
        if (t < len) {
            int lo = 0, hi = S;
            while (lo < hi) {
                const int mid = (lo + hi) >> 1;
                if (cum[mid] > t) hi = mid; else lo = mid + 1;
            }
            id = lo;                 // <= S-1 since cum[S-1] = len > t
        }
        fidx[b * T + t] = id;
        mask[b * T + t] = (id < 0) ? 1.0f : 0.0f;
    }
}

// ---------------- Kernel B: high-MLP streaming gather-copy ------------------
__global__ __launch_bounds__(256) void lr_copy_kernel(
    const float* __restrict__ x,     // [B, S, D]
    const int*   __restrict__ fidx,  // [B, T]
    float*       __restrict__ out)   // [B, T, D]
{
    __shared__ int fr[FPB];

    const int tid   = threadIdx.x;
    const int chunk = blockIdx.x;
    const int b     = blockIdx.y;
    const int t0    = chunk * FPB;

    if (tid < FPB) fr[tid] = fidx[b * T + t0 + tid];
    __syncthreads();

    const int wv   = tid >> 6;       // wave 0..3 -> frame sub-slot
    const int lane = tid & 63;       // float4 lane; covers j=lane and j=lane+64
    const floatx4* xb = (const floatx4*)(x + (size_t)b * S * D);
    floatx4*       ob = (floatx4*)(out + ((size_t)b * T + t0) * D);

    #pragma unroll 4
    for (int it = 0; it < FPB / 4; ++it) {   // 16 iters, 4 frames per iter
        const int tl = it * 4 + wv;          // wave-uniform frame
        const int id = fr[tl];
        floatx4 v0 = (floatx4)(0.f);
        floatx4 v1 = (floatx4)(0.f);
        if (id >= 0) {
            const floatx4* src = xb + (size_t)id * (D / 4);
            v0 = src[lane];
            v1 = src[lane + 64];
        }
        floatx4* dst = ob + (size_t)tl * (D / 4);
        __builtin_nontemporal_store(v0, dst + lane);
        __builtin_nontemporal_store(v1, dst + lane + 64);
    }
}

extern "C" void kernel_launch(void* const* d_in, const int* in_sizes, int n_in,
                              void* d_out, int out_size, void* d_ws, size_t ws_size,
                              hipStream_t stream) {
    const float* x   = (const float*)d_in[0];
    const int*   dur = (const int*)d_in[1];
    float* out  = (float*)d_out;
    float* mask = out + (size_t)B * T * D;   // outputs concatenated flat
    int*   fidx = (int*)d_ws;                // 512 KB scratch

    lr_scan_kernel<<<B, 256, 0, stream>>>(dur, fidx, mask);
    dim3 grid(CHUNKS, B);
    lr_copy_kernel<<<grid, 256, 0, stream>>>(x, fidx, out);
}

// Round 5
// 354.558 us; speedup vs baseline: 1.0372x; 1.0150x over previous
//
#include <hip/hip_runtime.h>

// LengthRegulator: B=64, S=1024, D=512, T=2048 (fixed by setup_inputs)
constexpr int B = 64;
constexpr int S = 1024;
constexpr int D = 512;
constexpr int T = 2048;
constexpr int FPB = 64;            // frames per block (copy kernel)
constexpr int CHUNKS = T / FPB;    // 32

typedef float floatx4 __attribute__((ext_vector_type(4)));

// ---------------- Kernel A: cumsum + searchsorted + mask (64 blocks) --------
__global__ __launch_bounds__(256) void lr_scan_kernel(
    const int* __restrict__ dur,    // [B, S]
    int*       __restrict__ fidx,   // [B, T]  (ws)  -1 => masked/zero row
    float*     __restrict__ mask)   // [B, T]
{
    __shared__ int cum[S];
    __shared__ int wave_tot[4];

    const int tid  = threadIdx.x;
    const int b    = blockIdx.x;
    const int lane = tid & 63;
    const int wv   = tid >> 6;

    const int4 d4 = ((const int4*)(dur + b * S))[tid];
    const int p0 = d4.x;
    const int p1 = p0 + d4.y;
    const int p2 = p1 + d4.z;
    const int p3 = p2 + d4.w;

    // shuffle-based inclusive scan of per-thread totals within each wave
    int incl = p3;
    #pragma unroll
    for (int off = 1; off < 64; off <<= 1) {
        const int v = __shfl_up(incl, off, 64);
        if (lane >= off) incl += v;
    }
    if (lane == 63) wave_tot[wv] = incl;   // wave total
    __syncthreads();
    int woff = 0;
    #pragma unroll
    for (int w = 0; w < 4; ++w) woff += (w < wv) ? wave_tot[w] : 0;

    const int excl = woff + incl - p3;     // exclusive prefix for this thread's 4 elems
    cum[4 * tid + 0] = excl + p0;
    cum[4 * tid + 1] = excl + p1;
    cum[4 * tid + 2] = excl + p2;
    cum[4 * tid + 3] = excl + p3;
    __syncthreads();
    const int len = cum[S - 1];

    #pragma unroll
    for (int k = 0; k < T / 256; ++k) {
        const int t = k * 256 + tid;
        int id = -1;
        if (t < len) {
            int lo = 0, hi = S;
            while (lo < hi) {
                const int mid = (lo + hi) >> 1;
                if (cum[mid] > t) hi = mid; else lo = mid + 1;
            }
            id = lo;                 // <= S-1 since cum[S-1] = len > t
        }
        fidx[b * T + t] = id;
        mask[b * T + t] = (id < 0) ? 1.0f : 0.0f;
    }
}

// ---------------- Kernel B: max-ILP streaming gather-copy -------------------
// One wave owns 16 consecutive frames; frame ids live in SGPRs; loads are
// register-blocked 8 frames at a time (16 dwordx4 in flight), then stored nt.
__global__ __launch_bounds__(256) void lr_copy_kernel(
    const float* __restrict__ x,     // [B, S, D]
    const int*   __restrict__ fidx,  // [B, T]
    float*       __restrict__ out)   // [B, T, D]
{
    __shared__ int fr[FPB];

    const int tid   = threadIdx.x;
    const int chunk = blockIdx.x;
    const int b     = blockIdx.y;
    const int t0    = chunk * FPB;

    if (tid < FPB) fr[tid] = fidx[b * T + t0 + tid];
    __syncthreads();

    const int wv   = tid >> 6;       // wave -> 16-frame span
    const int lane = tid & 63;
    const floatx4* xb = (const floatx4*)(x + (size_t)b * S * D);
    floatx4*       ob = (floatx4*)(out + ((size_t)b * T + t0) * D)
                        + (size_t)(wv * 16) * (D / 4);

    // hoist all 16 frame ids into scalar regs (one batched LDS wait)
    int sid[16];
    #pragma unroll
    for (int k = 0; k < 16; ++k)
        sid[k] = __builtin_amdgcn_readfirstlane(fr[wv * 16 + k]);

    #pragma unroll
    for (int batch = 0; batch < 2; ++batch) {
        floatx4 v[8][2];
        #pragma unroll
        for (int f = 0; f < 8; ++f) {
            const int id = sid[batch * 8 + f];
            v[f][0] = (floatx4)(0.f);
            v[f][1] = (floatx4)(0.f);
            if (id >= 0) {           // scalar branch; true ~always
                const floatx4* src = xb + (size_t)id * (D / 4);
                v[f][0] = src[lane];
                v[f][1] = src[lane + 64];
            }
        }
        #pragma unroll
        for (int f = 0; f < 8; ++f) {
            floatx4* dst = ob + (size_t)(batch * 8 + f) * (D / 4);
            __builtin_nontemporal_store(v[f][0], dst + lane);
            __builtin_nontemporal_store(v[f][1], dst + lane + 64);
        }
    }
}

extern "C" void kernel_launch(void* const* d_in, const int* in_sizes, int n_in,
                              void* d_out, int out_size, void* d_ws, size_t ws_size,
                              hipStream_t stream) {
    const float* x   = (const float*)d_in[0];
    const int*   dur = (const int*)d_in[1];
    float* out  = (float*)d_out;
    float* mask = out + (size_t)B * T * D;   // outputs concatenated flat
    int*   fidx = (int*)d_ws;                // 512 KB scratch

    lr_scan_kernel<<<B, 256, 0, stream>>>(dur, fidx, mask);
    dim3 grid(CHUNKS, B);
    lr_copy_kernel<<<grid, 256, 0, stream>>>(x, fidx, out);
}